// Round 4
// baseline (158.091 us; speedup 1.0000x reference)
//
#include <hip/hip_runtime.h>
#include <math.h>

#define NN 256
#define NS 512
#define MS 32
#define NSTEP 32
#define VRESET 1.0f

__device__ __forceinline__ float sigf(float x) {
    // fast sigmoid: v_exp_f32 + v_rcp_f32 (~3 ulp); validated R2/R3 (absmax 0.125)
    float e = __expf(-x);
    return __builtin_amdgcn_rcpf(1.0f + e);
}

// One block (256 threads = 4 waves) per sample; thread tid owns neuron tid.
// R4 changes vs R3:
//  (a) v,i RK4 is linear -> folded into per-round coefficients (fp64-computed,
//      fp32-rounded): stage args a2..a4 = 2 FMA each, v' = 2 FMA, i' = 1 mul.
//      ~1-2 ulp/step vs sequential fp32 RK4, damped by |R00|<1.
//  (b) trigger check delayed one step: ballot(st) -> LDS flag[st&1] before
//      barrier(st); read at top of iter st+1 (after barrier(st), before
//      barrier(st+1)) -> sigmoid tail/ballot/barrier off the critical path.
//      Event at step st-1 reconstructed exactly from saved (vp,ip,sp,tprev).
__global__ __launch_bounds__(256) void snn_kernel(
    const float* __restrict__ ic_g,     // (256,)
    const float* __restrict__ w,        // (256,256)
    const float* __restrict__ mu,       // (2,)
    const float* __restrict__ v0,       // (256,)
    const float* __restrict__ i0,       // (256,)
    const float* __restrict__ s0,       // (512,256)
    const float* __restrict__ reset_s,  // (32,512,256)
    const int*   __restrict__ t1p,      // scalar
    float* __restrict__ out)
{
    const int tid  = threadIdx.x;   // neuron index
    const int lane = tid & 63;
    const int wid  = tid >> 6;
    const int samp = blockIdx.x;
    const double m1d = (double)mu[0];
    const double m2d = (double)mu[1];
    const float t1f = (float)t1p[0];

    __shared__ int   s_any[2][4];   // per-step crossing flag, parity dbuf
    __shared__ float s_bv[4], s_bsp[4];
    __shared__ int   s_bn[4];
    __shared__ int   s_eidx[4];

    float v  = v0[tid];
    float ii = i0[tid];
    float s  = s0[samp * NN + tid];
    const float ic = ic_g[tid];
    float t0 = 0.0f;

    float* times = out;                                  // [NS][MS]
    float* vals  = out + (size_t)NS * MS;                // [NS][MS][NN][3]
    float* marks = out + (size_t)NS * MS * (1 + NN * 3); // [NS][MS][NN]

    for (int r = 0; r < MS; ++r) {
        const float dt = (t1f - t0) / (float)NSTEP;
        float tev = t1f;
        float yev_v, yev_i, yev_s;
        bool  em = false;
        bool  done = false;

        if (dt != 0.0f) {
            // ---- per-round linear-map coefficients (fp64 -> fp32) ----
            const double hd = (double)dt;
            const double a  = hd * m1d;          // h*mu1
            const double b  = hd * m2d;          // h*mu2
            const double p2 = 1.0 - 0.5 * a, q2 = 0.5 * a, r2 = 0.5 * a;
            const double i2c = 1.0 - 0.5 * b;
            const double p3 = 1.0 - 0.5 * a * p2;
            const double q3 = 0.5 * a * (i2c - q2);
            const double r3 = 0.5 * a * (1.0 - r2);
            const double i3c = 1.0 - 0.5 * b * i2c;
            const double p4 = 1.0 - a * p3;
            const double q4 = a * (i3c - q3);
            const double r4 = a * (1.0 - r3);
            const double i4c = 1.0 - b * i3c;
            const double a6 = a / 6.0, b6 = b / 6.0;
            const float fR00 = (float)(1.0 - a6 * (1.0 + 2.0 * p2 + 2.0 * p3 + p4));
            const float fR01 = (float)(a6 * (1.0 + 2.0 * (i2c - q2) + 2.0 * (i3c - q3) + (i4c - q4)));
            const float fC0  = (float)(a6 * (1.0 + 2.0 * (1.0 - r2) + 2.0 * (1.0 - r3) + (1.0 - r4)));
            const float fR11 = (float)(1.0 - b6 * (1.0 + 2.0 * i2c + 2.0 * i3c + i4c));
            const float fp2 = (float)p2, fq2 = (float)q2;
            const float fp3 = (float)p3, fq3 = (float)q3;
            const float fp4 = (float)p4, fq4 = (float)q4;
            const float r2ic = (float)r2 * ic;
            const float r3ic = (float)r3 * ic;
            const float r4ic = (float)r4 * ic;
            const float c0ic = fC0 * ic;
            const float h6 = dt * (1.0f / 6.0f);

            float t = t0, tprev = t0;
            float vp = v, ip = ii, sp = s;

            for (int st = 0; st <= NSTEP; ++st) {
                if (st > 0) {
                    // check step st-1's flag (written before barrier(st-1))
                    int anyflag = s_any[(st - 1) & 1][0] | s_any[(st - 1) & 1][1] |
                                  s_any[(st - 1) & 1][2] | s_any[(st - 1) & 1][3];
                    if (anyflag) {
                        // event at step st-1: y = (vp,ip,sp), y_new = (v,ii,s)
                        float bv = s, bsp = sp;
                        int   bn = tid;
#pragma unroll
                        for (int off = 32; off >= 1; off >>= 1) {
                            float ov  = __shfl_xor(bv, off);
                            float osp = __shfl_xor(bsp, off);
                            int   on  = __shfl_xor(bn, off);
                            if (ov > bv || (ov == bv && on < bn)) { bv = ov; bsp = osp; bn = on; }
                        }
                        if (lane == 0) { s_bv[wid] = bv; s_bsp[wid] = bsp; s_bn[wid] = bn; }
                        __syncthreads();
                        bv = s_bv[0]; bsp = s_bsp[0]; bn = s_bn[0];
#pragma unroll
                        for (int wv = 1; wv < 4; ++wv) {
                            float ov = s_bv[wv], osp = s_bsp[wv];
                            int   on = s_bn[wv];
                            if (ov > bv || (ov == bv && on < bn)) { bv = ov; bsp = osp; bn = on; }
                        }
                        float frac = bsp / (bsp - bv + 1e-12f);
                        frac = fminf(fmaxf(frac, 0.0f), 1.0f);
                        tev = tprev + frac * dt;
                        yev_v = vp + frac * (v  - vp);
                        yev_i = ip + frac * (ii - ip);
                        yev_s = sp + frac * (s  - sp);
                        em = s > 0.0f;
                        v = yev_v; ii = yev_i; s = yev_s;
                        done = true;
                        break;
                    }
                }
                if (st == NSTEP) break;

                // ---- compute step st from (v,ii,s) ----
                vp = v; ip = ii; sp = s; tprev = t;
                float a2 = fmaf(fp2, vp, fmaf(fq2, ip, r2ic));
                float a3 = fmaf(fp3, vp, fmaf(fq3, ip, r3ic));
                float a4 = fmaf(fp4, vp, fmaf(fq4, ip, r4ic));
                float k1 = sigf(vp);
                float k2 = sigf(a2);
                float k3 = sigf(a3);
                float k4 = sigf(a4);
                v  = fmaf(fR00, vp, fmaf(fR01, ip, c0ic));
                ii = fR11 * ip;
                float ts = fmaf(2.0f, k2, k1);
                ts = fmaf(2.0f, k3, ts);
                ts = ts + k4;
                s = fmaf(h6, ts, sp);

                unsigned long long bl = __ballot(s > 0.0f);
                if (lane == 0) s_any[st & 1][wid] = (bl != 0ull) ? 1 : 0;
                t = tprev + dt;
                __syncthreads();
            }
        }

        if (!done) {
            tev = t1f;
            yev_v = v; yev_i = ii; yev_s = s; em = false;
        }

        // ---- emit round outputs ----
        const int sr = samp * MS + r;
        if (tid == 0) times[sr] = tev;
        {
            float* p = vals + ((size_t)sr * NN + tid) * 3;
            p[0] = yev_v;
            p[1] = yev_i;
            p[2] = yev_s;
            marks[(size_t)sr * NN + tid] = em ? 1.0f : 0.0f;
        }

        // ---- reset for next round ----
        if (done) {
            unsigned long long bm = __ballot(em);
            int cand = (bm != 0ull) ? (wid * 64 + (int)__builtin_ctzll(bm)) : (2 * NN);
            if (lane == 0) s_eidx[wid] = cand;
            __syncthreads();
            int eidx = s_eidx[0];
            eidx = (s_eidx[1] < eidx) ? s_eidx[1] : eidx;
            eidx = (s_eidx[2] < eidx) ? s_eidx[2] : eidx;
            eidx = (s_eidx[3] < eidx) ? s_eidx[3] : eidx;

            float wr = w[eidx * NN + tid];
            v  = yev_v - (em ? VRESET : 0.0f);
            ii = yev_i + wr;
            float sres = em ? reset_s[((size_t)r * NS + samp) * NN + tid] : yev_s;
            s = fminf(sres, 0.0f);
        } else {
            s = fminf(s, 0.0f);
        }
        t0 = tev;
    }
}

extern "C" void kernel_launch(void* const* d_in, const int* in_sizes, int n_in,
                              void* d_out, int out_size, void* d_ws, size_t ws_size,
                              hipStream_t stream) {
    const float* ic      = (const float*)d_in[0];
    const float* w       = (const float*)d_in[1];
    const float* mu      = (const float*)d_in[2];
    const float* v0      = (const float*)d_in[3];
    const float* i0      = (const float*)d_in[4];
    const float* s0      = (const float*)d_in[5];
    const float* reset_s = (const float*)d_in[6];
    const int*   t1p     = (const int*)d_in[7];
    float* out = (float*)d_out;

    snn_kernel<<<dim3(NS), dim3(256), 0, stream>>>(ic, w, mu, v0, i0, s0,
                                                   reset_s, t1p, out);
}

// Round 5
// 155.916 us; speedup vs baseline: 1.0139x; 1.0139x over previous
//
#include <hip/hip_runtime.h>
#include <math.h>

#define NN 256
#define NS 512
#define MS 32
#define NSTEP 32
#define VRESET 1.0f

__device__ __forceinline__ float sigf(float x) {
    // fast sigmoid: v_exp_f32 + v_rcp_f32 (~3 ulp); validated R2-R4 (absmax 0.125)
    float e = __expf(-x);
    return __builtin_amdgcn_rcpf(1.0f + e);
}

// One block (256 threads = 4 waves) per sample; thread tid owns neuron tid.
// R5: NO per-step synchronization. Waves run ahead independently, writing an
// s-history to LDS; a wave stops on its OWN local crossing (__any, vcc only)
// and posts atomicMin(&s_stop, k). Other waves poll s_stop with a 1-iter-stale
// pipelined read (safe: hint step >= true st*, so history always covers st*).
// Once per round: barrier, reconcile at st* = s_stop — s from history, v/i by
// bit-identical replay of the linear recurrence (v,i independent of s).
__global__ __launch_bounds__(256) void snn_kernel(
    const float* __restrict__ ic_g,     // (256,)
    const float* __restrict__ w,        // (256,256)
    const float* __restrict__ mu,       // (2,)
    const float* __restrict__ v0,       // (256,)
    const float* __restrict__ i0,       // (256,)
    const float* __restrict__ s0,       // (512,256)
    const float* __restrict__ reset_s,  // (32,512,256)
    const int*   __restrict__ t1p,      // scalar
    float* __restrict__ out)
{
    const int tid  = threadIdx.x;   // neuron index
    const int lane = tid & 63;
    const int wid  = tid >> 6;
    const int samp = blockIdx.x;
    const double m1d = (double)mu[0];
    const double m2d = (double)mu[1];
    const float t1f = (float)t1p[0];

    __shared__ float s_hist[NSTEP + 1][NN];  // 33.8 KB: s after k steps
    __shared__ int   s_stop;                 // min crossing step this round
    __shared__ float s_bv[4], s_bsp[4];
    __shared__ int   s_bn[4], s_eidx[4];

    float v  = v0[tid];
    float ii = i0[tid];
    float s  = s0[samp * NN + tid];
    const float ic = ic_g[tid];
    float t0 = 0.0f;

    float* times = out;                                  // [NS][MS]
    float* vals  = out + (size_t)NS * MS;                // [NS][MS][NN][3]
    float* marks = out + (size_t)NS * MS * (1 + NN * 3); // [NS][MS][NN]

    for (int r = 0; r < MS; ++r) {
        const float dt = (t1f - t0) / (float)NSTEP;
        float tev = t1f;
        float yev_v, yev_i, yev_s;
        bool  em = false;
        bool  done = false;

        // prefetch this round's reset row (fire-and-forget; used only if em)
        const float rs_pref = reset_s[((size_t)r * NS + samp) * NN + tid];

        if (dt != 0.0f) {   // dt is block-uniform -> barriers below are safe
            // ---- per-round linear-map coefficients (fp64 -> fp32), as R4 ----
            const double hd = (double)dt;
            const double a  = hd * m1d;
            const double b  = hd * m2d;
            const double p2 = 1.0 - 0.5 * a, q2 = 0.5 * a, r2 = 0.5 * a;
            const double i2c = 1.0 - 0.5 * b;
            const double p3 = 1.0 - 0.5 * a * p2;
            const double q3 = 0.5 * a * (i2c - q2);
            const double r3 = 0.5 * a * (1.0 - r2);
            const double i3c = 1.0 - 0.5 * b * i2c;
            const double p4 = 1.0 - a * p3;
            const double q4 = a * (i3c - q3);
            const double r4 = a * (1.0 - r3);
            const double i4c = 1.0 - b * i3c;
            const double a6 = a / 6.0, b6 = b / 6.0;
            const float fR00 = (float)(1.0 - a6 * (1.0 + 2.0 * p2 + 2.0 * p3 + p4));
            const float fR01 = (float)(a6 * (1.0 + 2.0 * (i2c - q2) + 2.0 * (i3c - q3) + (i4c - q4)));
            const float fC0  = (float)(a6 * (1.0 + 2.0 * (1.0 - r2) + 2.0 * (1.0 - r3) + (1.0 - r4)));
            const float fR11 = (float)(1.0 - b6 * (1.0 + 2.0 * i2c + 2.0 * i3c + i4c));
            const float fp2 = (float)p2, fq2 = (float)q2;
            const float fp3 = (float)p3, fq3 = (float)q3;
            const float fp4 = (float)p4, fq4 = (float)q4;
            const float r2ic = (float)r2 * ic;
            const float r3ic = (float)r3 * ic;
            const float r4ic = (float)r4 * ic;
            const float c0ic = fC0 * ic;
            const float h6 = dt * (1.0f / 6.0f);

            if (tid == 0) s_stop = NSTEP + 1;
            s_hist[0][tid] = s;
            __syncthreads();   // B1: s_stop init + hist[0] ordered vs prev round

            // ---- free-running step loop: NO barriers, NO blocking LDS reads ----
            float vv = v, iv = ii, sv = s;
            int seen = NSTEP + 1;
            for (int k = 1; k <= NSTEP; ++k) {
                float a2 = fmaf(fp2, vv, fmaf(fq2, iv, r2ic));
                float a3 = fmaf(fp3, vv, fmaf(fq3, iv, r3ic));
                float a4 = fmaf(fp4, vv, fmaf(fq4, iv, r4ic));
                float k1 = sigf(vv);
                float k2 = sigf(a2);
                float k3 = sigf(a3);
                float k4 = sigf(a4);
                float vn  = fmaf(fR00, vv, fmaf(fR01, iv, c0ic));
                float in_ = fR11 * iv;
                float ts = fmaf(2.0f, k2, k1);
                ts = fmaf(2.0f, k3, ts);
                ts = ts + k4;
                sv = fmaf(h6, ts, sv);
                vv = vn; iv = in_;
                s_hist[k][tid] = sv;
                if (__any(sv > 0.0f)) {          // own 64 neurons crossed
                    if (lane == 0) atomicMin(&s_stop, k);
                    break;
                }
                if (seen <= k) break;            // stale hint: some wave crossed
                seen = *(volatile int*)&s_stop;  // pipelined poll (used next iter)
            }
            __syncthreads();   // B2: all histories + s_stop final
            const int st = s_stop;

            if (st <= NSTEP) {
                // ---- event at step st: reconcile from history + replay ----
                float sn_ = s_hist[st][tid];
                float sp_ = s_hist[st - 1][tid];
                em = sn_ > 0.0f;

                // block argmax of sn_ (value desc, index asc), carrying s_prev
                float bv = sn_, bsp = sp_;
                int   bn = tid;
#pragma unroll
                for (int off = 32; off >= 1; off >>= 1) {
                    float ov  = __shfl_xor(bv, off);
                    float osp = __shfl_xor(bsp, off);
                    int   on  = __shfl_xor(bn, off);
                    if (ov > bv || (ov == bv && on < bn)) { bv = ov; bsp = osp; bn = on; }
                }
                unsigned long long bm = __ballot(em);
                if (lane == 0) {
                    s_bv[wid] = bv; s_bsp[wid] = bsp; s_bn[wid] = bn;
                    s_eidx[wid] = (bm != 0ull) ? (wid * 64 + (int)__builtin_ctzll(bm))
                                               : (2 * NN);
                }
                __syncthreads();   // B3
                bv = s_bv[0]; bsp = s_bsp[0]; bn = s_bn[0];
#pragma unroll
                for (int wv = 1; wv < 4; ++wv) {
                    float ov = s_bv[wv], osp = s_bsp[wv];
                    int   on = s_bn[wv];
                    if (ov > bv || (ov == bv && on < bn)) { bv = ov; bsp = osp; bn = on; }
                }
                int eidx = s_eidx[0];
                eidx = (s_eidx[1] < eidx) ? s_eidx[1] : eidx;
                eidx = (s_eidx[2] < eidx) ? s_eidx[2] : eidx;
                eidx = (s_eidx[3] < eidx) ? s_eidx[3] : eidx;
                float wr = w[eidx * NN + tid];   // issue early; used at reset

                float frac = bsp / (bsp - bv + 1e-12f);
                frac = fminf(fmaxf(frac, 0.0f), 1.0f);

                // bit-exact replays of the sequential loop's t and (v,i)
                float tprev = t0;
                for (int q = 1; q < st; ++q) tprev += dt;
                tev = tprev + frac * dt;

                float rv = v, ri = ii;
                for (int q = 1; q < st; ++q) {
                    rv = fmaf(fR00, rv, fmaf(fR01, ri, c0ic));
                    ri = fR11 * ri;
                }
                float vnew = fmaf(fR00, rv, fmaf(fR01, ri, c0ic));
                float inew = fR11 * ri;
                yev_v = rv + frac * (vnew - rv);
                yev_i = ri + frac * (inew - ri);
                yev_s = sp_ + frac * (sn_ - sp_);
                done = true;

                // reset for next round
                v  = yev_v - (em ? VRESET : 0.0f);
                ii = yev_i + wr;
                s  = fminf(em ? rs_pref : yev_s, 0.0f);
            } else {
                // no trigger: end-of-round state is live in registers
                yev_v = vv; yev_i = iv; yev_s = sv;
                v = vv; ii = iv;
                s = fminf(sv, 0.0f);
            }
        } else {
            // dt == 0: RK4 is identity, no trigger possible
            yev_v = v; yev_i = ii; yev_s = s;
            s = fminf(s, 0.0f);
        }

        // ---- emit round outputs ----
        const int sr = samp * MS + r;
        if (tid == 0) times[sr] = tev;
        {
            float* p = vals + ((size_t)sr * NN + tid) * 3;
            p[0] = yev_v;
            p[1] = yev_i;
            p[2] = yev_s;
            marks[(size_t)sr * NN + tid] = em ? 1.0f : 0.0f;
        }
        t0 = tev;
    }
}

extern "C" void kernel_launch(void* const* d_in, const int* in_sizes, int n_in,
                              void* d_out, int out_size, void* d_ws, size_t ws_size,
                              hipStream_t stream) {
    const float* ic      = (const float*)d_in[0];
    const float* w       = (const float*)d_in[1];
    const float* mu      = (const float*)d_in[2];
    const float* v0      = (const float*)d_in[3];
    const float* i0      = (const float*)d_in[4];
    const float* s0      = (const float*)d_in[5];
    const float* reset_s = (const float*)d_in[6];
    const int*   t1p     = (const int*)d_in[7];
    float* out = (float*)d_out;

    snn_kernel<<<dim3(NS), dim3(256), 0, stream>>>(ic, w, mu, v0, i0, s0,
                                                   reset_s, t1p, out);
}